// Round 6
// baseline (928.099 us; speedup 1.0000x reference)
//
#include <hip/hip_runtime.h>
#include <hip/hip_fp16.h>
#include <stdint.h>

// ---------------------------------------------------------------------------
// Seq2SeqARDiffusion on MI355X.
//   k_prep_xh : pack [x_hist|emb] fp16 inputs for LSTM0, layout [t][b][12 u32]
//   k_prep_w  : pack LSTM weights into MFMA A-fragment order (+ W2, bias sums)
//   k_lstm0   : persistent MFMA LSTM layer 0, 64 WGs x 512 thr, 16 batch/WG
//   k_lstm1   : persistent MFMA LSTM layer 1 -> enc_out, same structure
//   k_diff    : persistent AR-diffusion, 32 WGs x 256 thr, TWO independent
//               16-batch chains per WG (latency interleave), MFMA 16x16x32.
// Round 6: LDS-only barriers (no vmcnt drain) in all persistent loops;
//          k_diff 2-chain interleave.
// ---------------------------------------------------------------------------

typedef __attribute__((ext_vector_type(2))) _Float16 half2_t;
typedef __attribute__((ext_vector_type(8))) _Float16 v8h;
typedef __attribute__((ext_vector_type(4))) float v4f;

#define DEV __device__ __forceinline__

// Barrier with LDS-only drain: skips the vmcnt(0) drain __syncthreads emits,
// so in-flight global stores/prefetches keep flowing across steps.
DEV void barrier_lds() {
  asm volatile("s_waitcnt lgkmcnt(0)\ns_barrier" ::: "memory");
}

DEV uint32_t pack2f(float a, float b) {
  __half ha = __float2half_rn(a), hb = __float2half_rn(b);
  return (uint32_t)__half_as_ushort(ha) | ((uint32_t)__half_as_ushort(hb) << 16);
}

DEV float2 up2(uint32_t u) {
  half2_t h = __builtin_bit_cast(half2_t, u);
  return make_float2((float)h.x, (float)h.y);
}

DEV float fast_ex2(float x) {
#if __has_builtin(__builtin_amdgcn_exp2f)
  return __builtin_amdgcn_exp2f(x);
#else
  return exp2f(x);
#endif
}
DEV float fast_rcp(float x) {
#if __has_builtin(__builtin_amdgcn_rcpf)
  return __builtin_amdgcn_rcpf(x);
#else
  return 1.f / x;
#endif
}
DEV float sigm(float x) { return fast_rcp(1.f + fast_ex2(-1.4426950408889634f * x)); }
DEV float tanh_f(float x) {
  return 2.f * fast_rcp(1.f + fast_ex2(-2.8853900817779268f * x)) - 1.f;
}

DEV uint32_t pk_add(uint32_t a, uint32_t b) {
  return __builtin_bit_cast(uint32_t,
      __builtin_bit_cast(half2_t, a) + __builtin_bit_cast(half2_t, b));
}

// relu(w*y + b), packed fp16
DEV uint32_t pk_relufma(uint32_t w, uint32_t y, uint32_t b) {
  half2_t r = __builtin_bit_cast(half2_t, w) * __builtin_bit_cast(half2_t, y) +
              __builtin_bit_cast(half2_t, b);
  half2_t z = {(_Float16)0.f, (_Float16)0.f};
#if __has_builtin(__builtin_elementwise_max)
  r = __builtin_elementwise_max(r, z);
#else
  uint32_t u = __builtin_bit_cast(uint32_t, r);
  uint32_t mask = ((u >> 15) & 1u) * 0xFFFFu | ((u >> 31) & 1u) * 0xFFFF0000u;
  r = __builtin_bit_cast(half2_t, u & ~mask);
#endif
  return __builtin_bit_cast(uint32_t, r);
}

DEV uint32_t cvtpk(float y) {
#if __has_builtin(__builtin_amdgcn_cvt_pkrtz)
  return __builtin_bit_cast(uint32_t, __builtin_amdgcn_cvt_pkrtz(y, y));
#else
  return pack2f(y, y);
#endif
}

// sum over each 16-lane row; lane (l&15)==15 of each row holds the row sum
DEV float rowsum16(float v) {
  int x;
  x = __builtin_amdgcn_update_dpp(0, __builtin_bit_cast(int, v), 0x111, 0xf, 0xf, true);
  v += __builtin_bit_cast(float, x);
  x = __builtin_amdgcn_update_dpp(0, __builtin_bit_cast(int, v), 0x112, 0xf, 0xf, true);
  v += __builtin_bit_cast(float, x);
  x = __builtin_amdgcn_update_dpp(0, __builtin_bit_cast(int, v), 0x114, 0xf, 0xf, true);
  v += __builtin_bit_cast(float, x);
  x = __builtin_amdgcn_update_dpp(0, __builtin_bit_cast(int, v), 0x118, 0xf, 0xf, true);
  v += __builtin_bit_cast(float, x);
  return v;
}

// ---------------- workspace layout (bytes) ----------------
static constexpr size_t OFF_XH  = 0;                 // 96*1024*12 u32 = 4,718,592
static constexpr size_t OFF_W0  = 4718592;           // w0A 40960 u32 = 163,840
static constexpr size_t OFF_BS0 = 4882432;           // 512 f32
static constexpr size_t OFF_W1L = 4884480;           // w1A 65536 u32 = 262,144
static constexpr size_t OFF_BS1 = 5146624;           // 512 f32
static constexpr size_t OFF_W2P = 5148672;           // 128*64 u32 = 32,768
static constexpr size_t OFF_ENC = 5181440;           // 1024*128 f32 = 524,288
static constexpr size_t OFF_YS0 = 5705728;           // 96*1024*128 half = 25,165,824
// total ~30.9 MB

// ---------------- prep: pack [x_hist | emb] as fp16 pairs ----------------
__global__ void k_prep_xh(const float* __restrict__ xh, const int* __restrict__ tix,
                          const float* __restrict__ temb, uint32_t* __restrict__ out) {
  int idx = blockIdx.x * 256 + threadIdx.x;          // 96*1024*12 total
  if (idx >= 96 * 1024 * 12) return;
  int m = idx % 12;
  int tb = idx / 12;
  int b = tb & 1023, t = tb >> 10;
  int k0 = 2 * m, k1 = k0 + 1;
  float v0 = (k0 < 8) ? xh[(b * 96 + t) * 8 + k0] : temb[tix[b] * 16 + (k0 - 8)];
  float v1 = (k1 < 8) ? xh[(b * 96 + t) * 8 + k1] : temb[tix[b] * 16 + (k1 - 8)];
  out[idx] = pack2f(v0, v1);
}

// ---------------- prep: pack weights ----------------
// A-fragment order for LSTM l: flat u32 idx = (((w*4+T)*NF + f)*64 + l)*4 + c
// content: lane l -> m=l&15, qf=l>>4; k = f*32 + qf*8 + 2c+{0,1};
// gate row g = (m&3)*128 + w*16 + (m>>2)*4 + T; K-cat = [x | h] (+ zero pad).
__global__ void k_prep_w(const float* __restrict__ Wih0, const float* __restrict__ Whh0,
                         const float* __restrict__ bih0, const float* __restrict__ bhh0,
                         const float* __restrict__ Wih1, const float* __restrict__ Whh1,
                         const float* __restrict__ bih1, const float* __restrict__ bhh1,
                         const float* __restrict__ W2,
                         uint32_t* __restrict__ w0p, uint32_t* __restrict__ w1p,
                         uint32_t* __restrict__ w2p, float* __restrict__ bs0,
                         float* __restrict__ bs1) {
  int idx = blockIdx.x * 256 + threadIdx.x;
  if (idx < 40960) {                       // w0A: NF=5, K=160 ([x24|h128|pad8])
    int w = idx / 5120;
    int r = idx % 5120;
    int T = r / 1280; r %= 1280;
    int f = r / 256;  r %= 256;
    int l = r >> 2, c = r & 3;
    int m = l & 15, qf = l >> 4;
    int g = (m & 3) * 128 + w * 16 + (m >> 2) * 4 + T;
    int k0 = f * 32 + qf * 8 + 2 * c, k1 = k0 + 1;
    float a = (k0 < 24) ? Wih0[g * 24 + k0] : ((k0 < 152) ? Whh0[g * 128 + k0 - 24] : 0.f);
    float b = (k1 < 24) ? Wih0[g * 24 + k1] : ((k1 < 152) ? Whh0[g * 128 + k1 - 24] : 0.f);
    w0p[idx] = pack2f(a, b);
  } else if (idx < 106496) {               // w1A: NF=8, K=256 ([ys0 128|h128])
    int i = idx - 40960;
    int w = i / 8192;
    int r = i % 8192;
    int T = r / 2048; r %= 2048;
    int f = r / 256;  r %= 256;
    int l = r >> 2, c = r & 3;
    int m = l & 15, qf = l >> 4;
    int g = (m & 3) * 128 + w * 16 + (m >> 2) * 4 + T;
    int k0 = f * 32 + qf * 8 + 2 * c, k1 = k0 + 1;
    float a = (k0 < 128) ? Wih1[g * 128 + k0] : Whh1[g * 128 + k0 - 128];
    float b = (k1 < 128) ? Wih1[g * 128 + k1] : Whh1[g * 128 + k1 - 128];
    w1p[i] = pack2f(a, b);
  } else if (idx < 114688) {               // W2: 128 x 64 u32 (row-major pairs)
    int i = idx - 106496;
    w2p[i] = pack2f(W2[2 * i], W2[2 * i + 1]);
  } else if (idx < 115200) {
    int i = idx - 114688;
    bs0[i] = bih0[i] + bhh0[i];
  } else if (idx < 115712) {
    int i = idx - 115200;
    bs1[i] = bih1[i] + bhh1[i];
  }
}

// ---------------- LSTM layer 0 (MFMA; 16 batch/WG, 64 WGs x 512) ----------------
// in tile: [x(0..23) | h(24..151) | pad(152..159)], stride 160 halfs = 320 B.
__global__ __launch_bounds__(512, 2) void k_lstm0(const uint32_t* __restrict__ xh16,
                                                  const uint32_t* __restrict__ w0A,
                                                  const float* __restrict__ bs0,
                                                  __half* __restrict__ ys0) {
  __shared__ __align__(16) __half inb[2][16][160];
  const int tid = threadIdx.x;
  const int w = tid >> 6, l = tid & 63;
  const int n = l & 15, ql = l >> 4;
  const int ju = w * 16 + ql * 4;
  const int bbase = blockIdx.x * 16;

  uint4 Af[4][5];
#pragma unroll
  for (int T = 0; T < 4; T++)
#pragma unroll
    for (int f = 0; f < 5; f++)
      Af[T][f] = ((const uint4*)w0A)[((w * 4 + T) * 5 + f) * 64 + l];
  float bias[4][4];
#pragma unroll
  for (int T = 0; T < 4; T++)
#pragma unroll
    for (int r = 0; r < 4; r++) bias[T][r] = bs0[r * 128 + ju + T];

  for (int i = tid; i < 2560; i += 512) ((uint32_t*)inb)[i] = 0u;  // zero both bufs
  __syncthreads();
  if (tid < 192) {  // stage x_0 into buf 0
    int b = tid / 12, m = tid % 12;
    ((uint32_t*)&inb[0][b][0])[m] = xh16[(0 * 1024 + bbase + b) * 12 + m];
  }
  float cst[4] = {0.f, 0.f, 0.f, 0.f};
  __syncthreads();

  for (int t = 0; t < 96; t++) {
    const int cur = t & 1, nxt = cur ^ 1;
    uint32_t sx = 0;
    int sb = 0, sm = 0;
    if (t < 95 && tid < 192) {           // prefetch x_{t+1} under the MFMAs
      sb = tid / 12; sm = tid % 12;
      sx = xh16[((t + 1) * 1024 + bbase + sb) * 12 + sm];
    }
    v4f acc[4];
#pragma unroll
    for (int T = 0; T < 4; T++) acc[T] = (v4f){0.f, 0.f, 0.f, 0.f};
#pragma unroll
    for (int f = 0; f < 5; f++) {
      uint4 bu = *(const uint4*)&inb[cur][n][f * 32 + ql * 8];
      v8h Bv = __builtin_bit_cast(v8h, bu);
#pragma unroll
      for (int T = 0; T < 4; T++)
        acc[T] = __builtin_amdgcn_mfma_f32_16x16x32_f16(
            __builtin_bit_cast(v8h, Af[T][f]), Bv, acc[T], 0, 0, 0);
    }
    float hv[4];
#pragma unroll
    for (int T = 0; T < 4; T++) {
      float gi = acc[T][0] + bias[T][0];
      float gf = acc[T][1] + bias[T][1];
      float gg = acc[T][2] + bias[T][2];
      float go = acc[T][3] + bias[T][3];
      float c = sigm(gf) * cst[T] + sigm(gi) * tanh_f(gg);
      cst[T] = c;
      hv[T] = sigm(go) * tanh_f(c);
    }
    uint32_t h01 = pack2f(hv[0], hv[1]), h23 = pack2f(hv[2], hv[3]);
    *(uint2*)&inb[nxt][n][24 + ju] = make_uint2(h01, h23);
    *(uint2*)((__half*)ys0 + (size_t)(t * 1024 + bbase + n) * 128 + ju) = make_uint2(h01, h23);
    if (t < 95 && tid < 192) ((uint32_t*)&inb[nxt][sb][0])[sm] = sx;
    barrier_lds();
  }
}

// ---------------- LSTM layer 1 (MFMA; 16 batch/WG, 64 WGs x 512) ----------------
// in tile: [ys0_t(0..127) | h(128..255) | pad], stride 264 halfs = 528 B.
__global__ __launch_bounds__(512, 2) void k_lstm1(const uint32_t* __restrict__ ys0u,
                                                  const uint32_t* __restrict__ w1A,
                                                  const float* __restrict__ bs1,
                                                  float* __restrict__ enc) {
  __shared__ __align__(16) __half inb[2][16][264];
  const int tid = threadIdx.x;
  const int w = tid >> 6, l = tid & 63;
  const int n = l & 15, ql = l >> 4;
  const int ju = w * 16 + ql * 4;
  const int bbase = blockIdx.x * 16;
  const int sb = tid >> 5, sc = tid & 31;   // staging: batch, 8B-chunk

  uint4 Af[4][8];
#pragma unroll
  for (int T = 0; T < 4; T++)
#pragma unroll
    for (int f = 0; f < 8; f++)
      Af[T][f] = ((const uint4*)w1A)[((w * 4 + T) * 8 + f) * 64 + l];
  float bias[4][4];
#pragma unroll
  for (int T = 0; T < 4; T++)
#pragma unroll
    for (int r = 0; r < 4; r++) bias[T][r] = bs1[r * 128 + ju + T];

  for (int i = tid; i < 4224; i += 512) ((uint32_t*)inb)[i] = 0u;
  __syncthreads();
  {  // stage ys0[t=0] into buf 0
    uint2 v = ((const uint2*)ys0u)[(size_t)(0 * 1024 + bbase + sb) * 32 + sc];
    *(uint2*)&inb[0][sb][sc * 4] = v;
  }
  float cst[4] = {0.f, 0.f, 0.f, 0.f};
  __syncthreads();

  for (int t = 0; t < 96; t++) {
    const int cur = t & 1, nxt = cur ^ 1;
    uint2 sv = make_uint2(0u, 0u);
    if (t < 95)                          // prefetch ys0[t+1] under the MFMAs
      sv = ((const uint2*)ys0u)[(size_t)((t + 1) * 1024 + bbase + sb) * 32 + sc];
    v4f acc[4];
#pragma unroll
    for (int T = 0; T < 4; T++) acc[T] = (v4f){0.f, 0.f, 0.f, 0.f};
#pragma unroll
    for (int f = 0; f < 8; f++) {
      uint4 bu = *(const uint4*)&inb[cur][n][f * 32 + ql * 8];
      v8h Bv = __builtin_bit_cast(v8h, bu);
#pragma unroll
      for (int T = 0; T < 4; T++)
        acc[T] = __builtin_amdgcn_mfma_f32_16x16x32_f16(
            __builtin_bit_cast(v8h, Af[T][f]), Bv, acc[T], 0, 0, 0);
    }
    float hv[4];
#pragma unroll
    for (int T = 0; T < 4; T++) {
      float gi = acc[T][0] + bias[T][0];
      float gf = acc[T][1] + bias[T][1];
      float gg = acc[T][2] + bias[T][2];
      float go = acc[T][3] + bias[T][3];
      float c = sigm(gf) * cst[T] + sigm(gi) * tanh_f(gg);
      cst[T] = c;
      hv[T] = sigm(go) * tanh_f(c);
    }
    *(uint2*)&inb[nxt][n][128 + ju] = make_uint2(pack2f(hv[0], hv[1]), pack2f(hv[2], hv[3]));
    if (t < 95) *(uint2*)&inb[nxt][sb][sc * 4] = sv;
    if (t == 95)
      *(float4*)&enc[(size_t)(bbase + n) * 128 + ju] = make_float4(hv[0], hv[1], hv[2], hv[3]);
    barrier_lds();
  }
}

// ---------------- AR diffusion: MFMA, 2 chains x 16 batches/WG, 4 waves --------
// W1 cols: [0:128) enc | [128:134) exo | [134:150) emb | 150 prev_y | 151 y |
//          [152:168) t_e | [168:184) h_e
// Round 6: two independent diffusion chains per WG interleaved to hide
// barrier/LDS/MFMA latency; LDS-only barrier.
__global__ __launch_bounds__(256, 1) void k_diff(
    const float* __restrict__ xfut, const float* __restrict__ y0,
    const int* __restrict__ tix, const float* __restrict__ noise,
    const float* __restrict__ temb, const float* __restrict__ W1,
    const float* __restrict__ b1, const float* __restrict__ b2,
    const float* __restrict__ W3, const float* __restrict__ b3,
    const uint32_t* __restrict__ w2p, const float* __restrict__ enc,
    float* __restrict__ out) {
  __shared__ uint32_t W1sL[128 * 65];                 // W1 cols 0..127 (stride 65)
  __shared__ uint32_t W1xL[128 * 29];                 // W1 cols 128..183 (stride 29)
  __shared__ uint32_t encPL[32 * 65];                 // enc fp16 pairs (stride 65)
  __shared__ uint32_t embPL[32 * 9];                  // emb fp16 pairs (stride 9)
  __shared__ float teL[100][16];
  __shared__ float2 ccL[100];
  __shared__ __align__(16) __half tprojL[100 * 128];  // [t][k]
  __shared__ __half hprojL[8 * 128];                  // [s][k]
  __shared__ __align__(16) float partL[2][2][4][16];  // [chain][buf][wave][m]
  __shared__ uint32_t encdL[2][256 * 17];             // [chain][thread*17+pi]

  const int tid = threadIdx.x;
  const int w = tid >> 6, l = tid & 63;
  const int m = l & 15, q = l >> 4;
  const int bbase = blockIdx.x * 32;

  // ---- stage W1 / enc / emb / tables ----
  for (int i = tid; i < 128 * 64; i += 256) {
    int r = i >> 6, c = i & 63;
    W1sL[r * 65 + c] = pack2f(W1[r * 184 + 2 * c], W1[r * 184 + 2 * c + 1]);
  }
  for (int i = tid; i < 128 * 28; i += 256) {
    int r = i / 28, c = i % 28;
    W1xL[r * 29 + c] = pack2f(W1[r * 184 + 128 + 2 * c], W1[r * 184 + 129 + 2 * c]);
  }
  for (int i = tid; i < 32 * 64; i += 256) {
    int bb = i >> 6, c = i & 63;
    encPL[bb * 65 + c] = pack2f(enc[(bbase + bb) * 128 + 2 * c],
                                enc[(bbase + bb) * 128 + 2 * c + 1]);
  }
  for (int i = tid; i < 32 * 8; i += 256) {
    int bb = i >> 3, c = i & 7;
    const float* er = temb + tix[bbase + bb] * 16;
    embPL[bb * 9 + c] = pack2f(er[2 * c], er[2 * c + 1]);
  }
  for (int p = tid; p < 1600; p += 256) {
    int tt = p >> 4, i = p & 15;
    float f = expf(-logf(10000.f) * (float)(i & 7) / 8.f);
    float a = (float)tt * f;
    teL[tt][i] = (i < 8) ? cosf(a) : sinf(a);
  }
  for (int qq = tid; qq < 100; qq += 256) {
    float ab = 1.f, beta = 0.f;
    for (int i = 0; i <= qq; i++) {
      beta = 1e-4f + (0.02f - 1e-4f) * (float)i / 99.f;
      ab *= (1.f - beta);
    }
    float cs, cd;
    if (qq == 0) { cs = sqrtf(1.f - ab); cd = 1.f / (sqrtf(ab) + 1e-8f); }
    else { cs = beta / (sqrtf(1.f - ab) + 1e-8f); cd = 1.f / (sqrtf(1.f - beta) + 1e-8f); }
    ccL[qq] = make_float2(cs, cd);
  }
  __syncthreads();

  // ---- tproj[t][k] = W1_te(row k).te[t] ; hproj[s][k] = W1_he(row k).te[s] ----
  {
    int k = tid & 127, hs = tid >> 7;   // hs: t-range half
    float wte[16], whe[16];
#pragma unroll
    for (int i = 0; i < 8; i++) {
      float2 a = up2(W1xL[k * 29 + 12 + i]);   // cols 152..167
      wte[2 * i] = a.x; wte[2 * i + 1] = a.y;
      float2 bqq = up2(W1xL[k * 29 + 20 + i]); // cols 168..183
      whe[2 * i] = bqq.x; whe[2 * i + 1] = bqq.y;
    }
    for (int tt = hs * 50; tt < hs * 50 + 50; tt++) {
      float s = 0.f;
#pragma unroll
      for (int i = 0; i < 16; i++) s += wte[i] * teL[tt][i];
      tprojL[tt * 128 + k] = __float2half_rn(s);
    }
    if (hs == 0) {
      for (int ss = 0; ss < 8; ss++) {
        float s = 0.f;
#pragma unroll
        for (int i = 0; i < 16; i++) s += whe[i] * teL[ss][i];
        hprojL[ss * 128 + k] = __float2half_rn(s);
      }
    }
  }

  // ---- per-lane constant part of base per chain ----
#pragma unroll
  for (int ch = 0; ch < 2; ch++) {
    for (int pi = 0; pi < 16; pi++) {
      int k0 = (pi >> 2) * 32 + q * 8 + (pi & 3) * 2;
      half2_t a0 = {(_Float16)0.f, (_Float16)0.f};
      half2_t a1 = a0;
      const uint32_t* wr0 = &W1sL[k0 * 65];
      const uint32_t* wr1 = &W1sL[(k0 + 1) * 65];
      const uint32_t* ep = &encPL[(ch * 16 + m) * 65];
#pragma unroll 8
      for (int c = 0; c < 64; c++) {
        half2_t e = __builtin_bit_cast(half2_t, ep[c]);
        a0 += __builtin_bit_cast(half2_t, wr0[c]) * e;
        a1 += __builtin_bit_cast(half2_t, wr1[c]) * e;
      }
#pragma unroll
      for (int c = 0; c < 8; c++) {
        half2_t e = __builtin_bit_cast(half2_t, embPL[(ch * 16 + m) * 9 + c]);
        a0 += __builtin_bit_cast(half2_t, W1xL[k0 * 29 + 3 + c]) * e;     // cols 134..149
        a1 += __builtin_bit_cast(half2_t, W1xL[(k0 + 1) * 29 + 3 + c]) * e;
      }
      float e0 = b1[k0] + (float)a0.x + (float)a0.y;
      float e1 = b1[k0 + 1] + (float)a1.x + (float)a1.y;
      encdL[ch][tid * 17 + pi] = pack2f(e0, e1);
    }
  }

  // ---- per-lane resident weights (shared by both chains) ----
  uint4 Bf[2][4];
  const uint4* w2u4 = (const uint4*)w2p;
#pragma unroll
  for (int tt = 0; tt < 2; tt++) {
    int n = w * 32 + tt * 16 + m;
#pragma unroll
    for (int f = 0; f < 4; f++) Bf[tt][f] = w2u4[n * 16 + f * 4 + q];
  }
  const float w3v0 = W3[w * 32 + m], w3v1 = W3[w * 32 + 16 + m];
  const float b2v0 = b2[w * 32 + m], b2v1 = b2[w * 32 + 16 + m];
  const float b3v = b3[0];

  uint32_t w1yP[16];
#pragma unroll
  for (int pi = 0; pi < 16; pi++) {
    int k0 = (pi >> 2) * 32 + q * 8 + (pi & 3) * 2;
    uint32_t ua = W1xL[k0 * 29 + 11];         // halfs: col150(lo), col151(hi)
    uint32_t ub = W1xL[(k0 + 1) * 29 + 11];
    w1yP[pi] = (ua >> 16) | (ub & 0xFFFF0000u);
  }

  float py0 = y0[bbase + m], py1 = y0[bbase + 16 + m];
  __syncthreads();

  int buf = 0;
  for (int s = 0; s < 8; s++) {
    // ---- base pairs for this AR step, per chain ----
    float xf0[6], xf1[6];
#pragma unroll
    for (int i = 0; i < 6; i++) {
      xf0[i] = xfut[((bbase + m) * 8 + s) * 6 + i];
      xf1[i] = xfut[((bbase + 16 + m) * 8 + s) * 6 + i];
    }
    uint32_t bph0[16], bph1[16];
#pragma unroll
    for (int pi = 0; pi < 16; pi++) {
      int k0 = (pi >> 2) * 32 + q * 8 + (pi & 3) * 2;
      float2 ed0 = up2(encdL[0][tid * 17 + pi]);
      float2 ed1 = up2(encdL[1][tid * 17 + pi]);
      float e00 = ed0.x, e01 = ed0.y, e10 = ed1.x, e11 = ed1.y;
#pragma unroll
      for (int c = 0; c < 3; c++) {
        float2 w0v = up2(W1xL[k0 * 29 + c]);        // cols 128..133 (exo)
        float2 w1v = up2(W1xL[(k0 + 1) * 29 + c]);
        e00 += w0v.x * xf0[2 * c] + w0v.y * xf0[2 * c + 1];
        e01 += w1v.x * xf0[2 * c] + w1v.y * xf0[2 * c + 1];
        e10 += w0v.x * xf1[2 * c] + w0v.y * xf1[2 * c + 1];
        e11 += w1v.x * xf1[2 * c] + w1v.y * xf1[2 * c + 1];
      }
      float wp0 = up2(W1xL[k0 * 29 + 11]).x;        // col 150
      float wp1 = up2(W1xL[(k0 + 1) * 29 + 11]).x;
      e00 += wp0 * py0;  e01 += wp1 * py0;
      e10 += wp0 * py1;  e11 += wp1 * py1;
      float hp0 = (float)hprojL[s * 128 + k0];
      float hp1 = (float)hprojL[s * 128 + k0 + 1];
      bph0[pi] = pack2f(e00 + hp0, e01 + hp1);
      bph1[pi] = pack2f(e10 + hp0, e11 + hp1);
    }

    float ya = noise[s * 1024 + bbase + m];
    float yb = noise[s * 1024 + bbase + 16 + m];
    // preload t=99 tproj/cc and fold into bt = bph + tproj
    uint32_t bt0[16], bt1[16];
    {
      const uint4* tb = (const uint4*)(tprojL + 99 * 128 + q * 8);
      uint4 t0 = tb[0], t1 = tb[4], t2 = tb[8], t3 = tb[12];
      uint32_t tv[16] = {t0.x, t0.y, t0.z, t0.w, t1.x, t1.y, t1.z, t1.w,
                         t2.x, t2.y, t2.z, t2.w, t3.x, t3.y, t3.z, t3.w};
#pragma unroll
      for (int pi = 0; pi < 16; pi++) {
        bt0[pi] = pk_add(bph0[pi], tv[pi]);
        bt1[pi] = pk_add(bph1[pi], tv[pi]);
      }
    }
    float2 ccv = ccL[99];

    for (int t = 99; t >= 0; t--) {
      // ---- chain A + chain B MFMAs (independent, interleaved by scheduler) ----
      uint32_t yPa = cvtpk(ya), yPb = cvtpk(yb);
      v4f d00 = {0.f, 0.f, 0.f, 0.f}, d01 = d00, d10 = d00, d11 = d00;
#pragma unroll
      for (int f = 0; f < 4; f++) {
        uint4 au;
        au.x = pk_relufma(w1yP[4 * f + 0], yPa, bt0[4 * f + 0]);
        au.y = pk_relufma(w1yP[4 * f + 1], yPa, bt0[4 * f + 1]);
        au.z = pk_relufma(w1yP[4 * f + 2], yPa, bt0[4 * f + 2]);
        au.w = pk_relufma(w1yP[4 * f + 3], yPa, bt0[4 * f + 3]);
        v8h A = __builtin_bit_cast(v8h, au);
        d00 = __builtin_amdgcn_mfma_f32_16x16x32_f16(A, __builtin_bit_cast(v8h, Bf[0][f]), d00, 0, 0, 0);
        d01 = __builtin_amdgcn_mfma_f32_16x16x32_f16(A, __builtin_bit_cast(v8h, Bf[1][f]), d01, 0, 0, 0);
        uint4 av;
        av.x = pk_relufma(w1yP[4 * f + 0], yPb, bt1[4 * f + 0]);
        av.y = pk_relufma(w1yP[4 * f + 1], yPb, bt1[4 * f + 1]);
        av.z = pk_relufma(w1yP[4 * f + 2], yPb, bt1[4 * f + 2]);
        av.w = pk_relufma(w1yP[4 * f + 3], yPb, bt1[4 * f + 3]);
        v8h Ab = __builtin_bit_cast(v8h, av);
        d10 = __builtin_amdgcn_mfma_f32_16x16x32_f16(Ab, __builtin_bit_cast(v8h, Bf[0][f]), d10, 0, 0, 0);
        d11 = __builtin_amdgcn_mfma_f32_16x16x32_f16(Ab, __builtin_bit_cast(v8h, Bf[1][f]), d11, 0, 0, 0);
      }
      // ---- prefetch next step's tproj/cc (off critical path) ----
      const int tn = (t > 0) ? t - 1 : 0;
      const uint4* tb = (const uint4*)(tprojL + tn * 128 + q * 8);
      uint4 t0 = tb[0], t1 = tb[4], t2 = tb[8], t3 = tb[12];
      float2 ccn = ccL[tn];
      // ---- epilogues ----
      float pra[4], prb[4];
#pragma unroll
      for (int r = 0; r < 4; r++) {
        pra[r] = fmaxf(d00[r] + b2v0, 0.f) * w3v0 + fmaxf(d01[r] + b2v1, 0.f) * w3v1;
        pra[r] = rowsum16(pra[r]);
        prb[r] = fmaxf(d10[r] + b2v0, 0.f) * w3v0 + fmaxf(d11[r] + b2v1, 0.f) * w3v1;
        prb[r] = rowsum16(prb[r]);
      }
      if ((l & 15) == 15) {
        *(float4*)&partL[0][buf][w][q * 4] = make_float4(pra[0], pra[1], pra[2], pra[3]);
        *(float4*)&partL[1][buf][w][q * 4] = make_float4(prb[0], prb[1], prb[2], prb[3]);
      }
      // fold tproj[tn] into btn while the barrier settles
      uint32_t tv[16] = {t0.x, t0.y, t0.z, t0.w, t1.x, t1.y, t1.z, t1.w,
                         t2.x, t2.y, t2.z, t2.w, t3.x, t3.y, t3.z, t3.w};
      uint32_t btn0[16], btn1[16];
#pragma unroll
      for (int pi = 0; pi < 16; pi++) {
        btn0[pi] = pk_add(bph0[pi], tv[pi]);
        btn1[pi] = pk_add(bph1[pi], tv[pi]);
      }
      barrier_lds();
      float eps0 = b3v + ((partL[0][buf][0][m] + partL[0][buf][1][m]) +
                          (partL[0][buf][2][m] + partL[0][buf][3][m]));
      float eps1 = b3v + ((partL[1][buf][0][m] + partL[1][buf][1][m]) +
                          (partL[1][buf][2][m] + partL[1][buf][3][m]));
      ya = (ya - ccv.x * eps0) * ccv.y;
      yb = (yb - ccv.x * eps1) * ccv.y;
      ccv = ccn;
#pragma unroll
      for (int pi = 0; pi < 16; pi++) { bt0[pi] = btn0[pi]; bt1[pi] = btn1[pi]; }
      buf ^= 1;
    }
    if (w == 0 && l < 16) out[(bbase + l) * 8 + s] = ya;
    if (w == 1 && l < 16) out[(bbase + 16 + l) * 8 + s] = yb;
    py0 = ya;
    py1 = yb;
  }
}

// ---------------------------------------------------------------------------
extern "C" void kernel_launch(void* const* d_in, const int* in_sizes, int n_in,
                              void* d_out, int out_size, void* d_ws, size_t ws_size,
                              hipStream_t stream) {
  const float* x_hist    = (const float*)d_in[0];
  const float* x_future  = (const float*)d_in[1];
  const float* y0        = (const float*)d_in[2];
  const int*   turb_idx  = (const int*)d_in[3];
  const float* init_noise = (const float*)d_in[5];
  const float* turb_emb  = (const float*)d_in[6];
  const float* W_ih0     = (const float*)d_in[7];
  const float* W_hh0     = (const float*)d_in[8];
  const float* b_ih0     = (const float*)d_in[9];
  const float* b_hh0     = (const float*)d_in[10];
  const float* W_ih1     = (const float*)d_in[11];
  const float* W_hh1     = (const float*)d_in[12];
  const float* b_ih1     = (const float*)d_in[13];
  const float* b_hh1     = (const float*)d_in[14];
  const float* W1        = (const float*)d_in[15];
  const float* b1        = (const float*)d_in[16];
  const float* W2        = (const float*)d_in[17];
  const float* b2        = (const float*)d_in[18];
  const float* W3        = (const float*)d_in[19];
  const float* b3        = (const float*)d_in[20];

  char* ws = (char*)d_ws;
  uint32_t* xh16 = (uint32_t*)(ws + OFF_XH);
  uint32_t* w0p  = (uint32_t*)(ws + OFF_W0);
  float*    bs0  = (float*)(ws + OFF_BS0);
  uint32_t* w1p  = (uint32_t*)(ws + OFF_W1L);
  float*    bs1  = (float*)(ws + OFF_BS1);
  uint32_t* w2p  = (uint32_t*)(ws + OFF_W2P);
  float*    encf = (float*)(ws + OFF_ENC);
  __half*   ys0h = (__half*)(ws + OFF_YS0);

  k_prep_xh<<<4608, 256, 0, stream>>>(x_hist, turb_idx, turb_emb, xh16);
  k_prep_w<<<452, 256, 0, stream>>>(W_ih0, W_hh0, b_ih0, b_hh0,
                                    W_ih1, W_hh1, b_ih1, b_hh1,
                                    W2, w0p, w1p, w2p, bs0, bs1);
  k_lstm0<<<64, 512, 0, stream>>>(xh16, w0p, bs0, ys0h);
  k_lstm1<<<64, 512, 0, stream>>>((const uint32_t*)ys0h, w1p, bs1, encf);
  k_diff<<<32, 256, 0, stream>>>(x_future, y0, turb_idx, init_noise, turb_emb,
                                 W1, b1, b2, W3, b3, w2p, encf, (float*)d_out);
}